// Round 5
// baseline (347.991 us; speedup 1.0000x reference)
//
#include <hip/hip_runtime.h>

// Problem constants: B=256, NT=301, D=96, NSEG=50
// linspace(1,301,51) -> segment s = rows [6s, 6s+6] (7 rows).
// v5: 2560 blocks x 256 threads; each block = (batch, chunk of 5 segments).
//   Stage 31 rows ONCE via float4, repack PER-SEGMENT column-major (CS=12,
//   16B-aligned -> 2x ds_read_b128 per 7-float column, 2-way bank alias =
//   free). Theory: plateau is LDS round-trip serialization between stores;
//   halve LDS issues + raise occupancy (23KB LDS, VGPR<=102 -> ~20 waves/CU).
#define BB 256
#define NT_ 301
#define DD 96
#define NSEG 50
#define NTRI (DD * (DD - 1) / 2)   // 4560
#define OUTD (DD + NTRI)           // 4656
#define CHUNK 5                    // segments per block
#define NCH (NSEG / CHUNK)         // 10 chunks per batch
#define CROWS (6 * CHUNK + 1)      // 31 rows staged per block
#define CS 12                      // per-segment column stride (floats)
#define SEGF (DD * CS)             // 1152 floats per packed segment

// Levy area, algebraically reduced (si[t]*sj[t] cross terms cancel):
//   A_ij = 0.5 * [ sum_{t=1..5} (si[t]*sj[t+1] - si[t+1]*sj[t])
//                  + sj[0]*(si[6]-si[1]) - si[0]*(sj[6]-sj[1]) ]
// 0.5 folded into the per-thread row cache.

__global__ __launch_bounds__(256, 5)
void logsig_kernel(const float* __restrict__ inp, float* __restrict__ out) {
    const int bc = blockIdx.x;          // 0 .. BB*NCH-1
    const int b  = bc / NCH;
    const int ch = bc - b * NCH;

    // segp[sl][c][t] = inp[b, 30*ch + 6*sl + t, c];  t in [0,7), slot 7..11 pad
    __shared__ float segp[CHUNK * SEGF];    // 23040 B

    // Stage: float4 coalesced loads, scatter into per-segment packed layout.
    // Row r belongs to segment(s) sl with 6sl <= r <= 6sl+6:
    //   sl in [(r-1)/6 , min(r/6, CHUNK-1)]  (boundary rows hit 2 segments).
    const float4* __restrict__ src4 = reinterpret_cast<const float4*>(
        inp + ((size_t)b * NT_ + (size_t)(30 * ch)) * DD);
    for (int idx = threadIdx.x; idx < CROWS * (DD / 4); idx += 256) {
        const int r  = idx / (DD / 4);      // 0..30
        const int q4 = idx - r * (DD / 4);  // 0..23 (float4 index within row)
        const float4 v = src4[idx];
        const int sl_hi = min(r / 6, CHUNK - 1);
        const int sl_lo = (r - 1) / 6;      // r=0 -> 0 (trunc toward zero)
        for (int sl = sl_lo; sl <= sl_hi; ++sl) {
            const int t = r - 6 * sl;       // 0..6
            float* d = &segp[sl * SEGF + (q4 * 4) * CS + t];
            d[0] = v.x; d[CS] = v.y; d[2 * CS] = v.z; d[3 * CS] = v.w;
        }
    }
    __syncthreads();

    const int ty = threadIdx.x >> 4;    // 0..15
    const int tx = threadIdx.x & 15;    // 0..15

    // triu(k=1) row bases (segment-independent)
    int rowoff[6];
    #pragma unroll
    for (int ti = 0; ti < 6; ++ti) {
        const int i = 16 * ti + ty;
        rowoff[ti] = DD + (i * (2 * DD - 1 - i)) / 2 - i - 1;
    }

    float* __restrict__ obase = out + ((size_t)b * NSEG + (size_t)ch * CHUNK) * OUTD;

    #pragma unroll 1
    for (int sl = 0; sl < CHUNK; ++sl) {
        const float* __restrict__ sp = &segp[sl * SEGF];
        float* __restrict__ o = obase + (size_t)sl * OUTD;

        // Row cache: 6 rows i = 16*ti+ty, pre-scaled by 0.5 (48 VGPRs).
        // 2x ds_read_b128 per row (16B-aligned: 48*i bytes).
        float rs[6][8];
        #pragma unroll
        for (int ti = 0; ti < 6; ++ti) {
            const int i = 16 * ti + ty;
            const float4 lo = *reinterpret_cast<const float4*>(&sp[i * CS]);
            const float4 hi = *reinterpret_cast<const float4*>(&sp[i * CS + 4]);
            rs[ti][0] = 0.5f * lo.x; rs[ti][1] = 0.5f * lo.y;
            rs[ti][2] = 0.5f * lo.z; rs[ti][3] = 0.5f * lo.w;
            rs[ti][4] = 0.5f * hi.x; rs[ti][5] = 0.5f * hi.y;
            rs[ti][6] = 0.5f * hi.z;
            rs[ti][7] = rs[ti][6] - rs[ti][1];             // 0.5*(s6-s1)
        }

        #pragma unroll
        for (int tj = 0; tj < 6; ++tj) {
            const int j = 16 * tj + tx;
            const float4 lo = *reinterpret_cast<const float4*>(&sp[j * CS]);
            const float4 hi = *reinterpret_cast<const float4*>(&sp[j * CS + 4]);
            const float c0 = lo.x, c1 = lo.y, c2 = lo.z, c3 = lo.w;
            const float c4 = hi.x, c5 = hi.y, c6 = hi.z;   // [7] is pad
            const float uj = c6 - c1;
            if (ty == 0)
                o[j] = c6 - c0;                            // lvl1 (unscaled)
            #pragma unroll
            for (int ti = 0; ti <= tj; ++ti) {
                // full tiles (ti<tj): always; diagonal: j>i <=> tx>ty
                if (ti < tj || tx > ty) {
                    float acc  = rs[ti][7] * c0 - rs[ti][0] * uj;
                    acc += rs[ti][1] * c2 - rs[ti][2] * c1;
                    acc += rs[ti][2] * c3 - rs[ti][3] * c2;
                    acc += rs[ti][3] * c4 - rs[ti][4] * c3;
                    acc += rs[ti][4] * c5 - rs[ti][5] * c4;
                    acc += rs[ti][5] * c6 - rs[ti][6] * c5;
                    o[rowoff[ti] + j] = acc;
                }
            }
        }
    }
}

extern "C" void kernel_launch(void* const* d_in, const int* in_sizes, int n_in,
                              void* d_out, int out_size, void* d_ws, size_t ws_size,
                              hipStream_t stream) {
    const float* inp = (const float*)d_in[0];
    float* out = (float*)d_out;
    logsig_kernel<<<BB * NCH, 256, 0, stream>>>(inp, out);
}

// Round 6
// 300.682 us; speedup vs baseline: 1.1573x; 1.1573x over previous
//
#include <hip/hip_runtime.h>

// Problem constants: B=256, NT=301, D=96, NSEG=50
// linspace(1,301,51) -> segment s = rows [6s, 6s+6] (7 rows).
// v6 = v4 REVERT (measured best, gap ~123 us): 512 blocks x 512 threads,
//   one block per (batch, half); stage 151 rows col-major once, two
//   256-thread groups sweep 25 segments with the register-cached algebra.
//   v5's regression traced to __launch_bounds__(256,5) VGPR cap -> spills;
//   no min-waves clause here (v4 measured: no spill, 2 blocks/CU, 16 waves).
#define BB 256
#define NT_ 301
#define DD 96
#define NSEG 50
#define NTRI (DD * (DD - 1) / 2)   // 4560
#define OUTD (DD + NTRI)           // 4656
#define HSEG 25                    // segments per block
#define HROWS 151                  // rows staged per block (6*25+1)
#define CSTR 154                   // LDS column stride (floats): even (8B align
                                   // for float2); 154%32=26 -> consecutive
                                   // columns spread banks (gcd(26,32)=2).

// Levy area, algebraically reduced (si[t]*sj[t] cross terms cancel):
//   A_ij = 0.5 * [ sum_{t=1..5} (si[t]*sj[t+1] - si[t+1]*sj[t])
//                  + sj[0]*(si[6]-si[1]) - si[0]*(sj[6]-sj[1]) ]
// 0.5 folded into the per-thread row cache.

__global__ __launch_bounds__(512)
void logsig_kernel(const float* __restrict__ inp, float* __restrict__ out) {
    const int bh = blockIdx.x;          // 0 .. 511
    const int b  = bh >> 1;
    const int h  = bh & 1;

    // colp[d*CSTR + t] = inp[b, h*150 + t, d], t in [0,151)
    __shared__ float colp[DD * CSTR];   // 96*154*4 = 59136 B

    const float* __restrict__ src = inp + ((size_t)b * NT_ + (size_t)(150 * h)) * DD;
    for (int idx = threadIdx.x; idx < HROWS * DD; idx += 512) {
        const int r = idx / DD;         // magic-mul (constant divisor)
        const int c = idx - r * DD;
        colp[c * CSTR + r] = src[idx];
    }
    __syncthreads();

    const int g    = threadIdx.x >> 8;  // group 0/1, each 256 threads
    const int t256 = threadIdx.x & 255;
    const int ty   = t256 >> 4;         // 0..15
    const int tx   = t256 & 15;         // 0..15

    // triu(k=1) row bases (segment-independent)
    int rowoff[6];
    #pragma unroll
    for (int ti = 0; ti < 6; ++ti) {
        const int i = 16 * ti + ty;
        rowoff[ti] = DD + (i * (2 * DD - 1 - i)) / 2 - i - 1;
    }

    #pragma unroll 1
    for (int sl = g; sl < HSEG; sl += 2) {
        const int t0 = 6 * sl;          // even -> 8B-aligned float2 reads
        float* __restrict__ o = out + ((size_t)(b * NSEG + h * HSEG + sl)) * OUTD;

        // Row cache: 6 rows i = 16*ti+ty, pre-scaled by 0.5 (48 VGPRs).
        float rs[6][8];
        #pragma unroll
        for (int ti = 0; ti < 6; ++ti) {
            const int i = 16 * ti + ty;
            const float2* __restrict__ p =
                reinterpret_cast<const float2*>(&colp[i * CSTR + t0]);
            const float2 v0 = p[0], v1 = p[1], v2 = p[2];
            const float  v6 = colp[i * CSTR + t0 + 6];
            rs[ti][0] = 0.5f * v0.x; rs[ti][1] = 0.5f * v0.y;
            rs[ti][2] = 0.5f * v1.x; rs[ti][3] = 0.5f * v1.y;
            rs[ti][4] = 0.5f * v2.x; rs[ti][5] = 0.5f * v2.y;
            rs[ti][6] = 0.5f * v6;
            rs[ti][7] = rs[ti][6] - rs[ti][1];             // 0.5*(s6-s1)
        }

        #pragma unroll
        for (int tj = 0; tj < 6; ++tj) {
            const int j = 16 * tj + tx;
            const float2* __restrict__ q =
                reinterpret_cast<const float2*>(&colp[j * CSTR + t0]);
            const float2 w0 = q[0], w1 = q[1], w2 = q[2];
            const float  c0 = w0.x, c1 = w0.y, c2 = w1.x, c3 = w1.y;
            const float  c4 = w2.x, c5 = w2.y;
            const float  c6 = colp[j * CSTR + t0 + 6];
            const float  uj = c6 - c1;
            if (ty == 0)
                o[j] = c6 - c0;                            // lvl1 (unscaled)
            #pragma unroll
            for (int ti = 0; ti <= tj; ++ti) {
                // full tiles (ti<tj): always; diagonal: j>i <=> tx>ty
                if (ti < tj || tx > ty) {
                    float acc  = rs[ti][7] * c0 - rs[ti][0] * uj;
                    acc += rs[ti][1] * c2 - rs[ti][2] * c1;
                    acc += rs[ti][2] * c3 - rs[ti][3] * c2;
                    acc += rs[ti][3] * c4 - rs[ti][4] * c3;
                    acc += rs[ti][4] * c5 - rs[ti][5] * c4;
                    acc += rs[ti][5] * c6 - rs[ti][6] * c5;
                    o[rowoff[ti] + j] = acc;
                }
            }
        }
    }
}

extern "C" void kernel_launch(void* const* d_in, const int* in_sizes, int n_in,
                              void* d_out, int out_size, void* d_ws, size_t ws_size,
                              hipStream_t stream) {
    const float* inp = (const float*)d_in[0];
    float* out = (float*)d_out;
    logsig_kernel<<<2 * BB, 512, 0, stream>>>(inp, out);
}